// Round 10
// baseline (505.853 us; speedup 1.0000x reference)
//
#include <hip/hip_runtime.h>
#include <hip/hip_bf16.h>

typedef _Float16 f16;
typedef _Float16 f16x8 __attribute__((ext_vector_type(8)));
typedef _Float16 f16x4 __attribute__((ext_vector_type(4)));
typedef float    f32x4 __attribute__((ext_vector_type(4)));

#define HDIM 128
#define IDIM 4
#define TLEN 512

#if __has_builtin(__builtin_amdgcn_rcpf)
__device__ __forceinline__ float frcp(float x){ return __builtin_amdgcn_rcpf(x); }
#else
__device__ __forceinline__ float frcp(float x){ return 1.0f / x; }
#endif

__device__ __forceinline__ float sigm(float x){
  return frcp(1.0f + __builtin_exp2f(x * -1.442695041f));
}
__device__ __forceinline__ float tanh_fast(float x){
  return 1.0f - 2.0f * frcp(1.0f + __builtin_exp2f(x * 2.885390082f));
}

// Block = 1 direction x 2 chains; 8 waves; wave w owns gate tiles
// {w,w+8,w+16,w+24} (all 4 gates of units [16w,16w+16)).
// K=128 MFMA (no K-ext): input projection + bias computed on the VALU
// per column and injected via the MFMA C-init {xw0,xw1,0,0}.
// h exchanged via LDS in A-frag layout (rows>=2 zero); 1 barrier/step;
// dual-chain activation on lanes 0-15 (acc .x/.y), no bpermute.
__global__ __launch_bounds__(512, 2) void bilstm_v7(
    const float* __restrict__ x,
    const float* __restrict__ Wih_f, const float* __restrict__ Whh_f,
    const float* __restrict__ bih_f, const float* __restrict__ bhh_f,
    const float* __restrict__ Wih_b, const float* __restrict__ Whh_b,
    const float* __restrict__ bih_b, const float* __restrict__ bhh_b,
    float* __restrict__ out)
{
  __shared__ __align__(16) float xs[2][TLEN][IDIM]; // 16 KB x (f32), both chains
  __shared__ __align__(16) f16 ha[2][4][64][8];     //  8 KB h in A-frag layout, dbuf

  const int tid = threadIdx.x;
  const int w   = tid >> 6;        // wave 0..7
  const int l   = tid & 63;
  const int c16 = l & 15;
  const int dir = blockIdx.x >> 7;
  const int b0  = (blockIdx.x & 127) * 2;

  const float* Wih = dir ? Wih_b : Wih_f;
  const float* Whh = dir ? Whh_b : Whh_f;
  const float* bih = dir ? bih_b : bih_f;
  const float* bhh = dir ? bhh_b : bhh_f;

  // ---- one-time: B fragments (4 tiles x 4 K-frags, Whh^T only) + per-column
  //      input-projection rows and combined bias in VGPRs ----
  f16x8 bfrag[4][4];
  float4 wih[4];
  float  bias[4];
  #pragma unroll
  for (int t = 0; t < 4; ++t){
    const int gn = t*128 + w*16 + c16;
    #pragma unroll
    for (int ks = 0; ks < 4; ++ks){
      const float* p = Whh + gn*HDIM + ks*32 + (l>>4)*8;
      float4 qa = ((const float4*)p)[0];
      float4 qb = ((const float4*)p)[1];
      f16x8 v = { (f16)qa.x,(f16)qa.y,(f16)qa.z,(f16)qa.w,
                  (f16)qb.x,(f16)qb.y,(f16)qb.z,(f16)qb.w };
      bfrag[t][ks] = v;
    }
    wih[t]  = *(const float4*)(Wih + gn*IDIM);
    bias[t] = bih[gn] + bhh[gn];
  }
  #pragma unroll
  for (int t = 0; t < 4; ++t)
    #pragma unroll
    for (int ks = 0; ks < 4; ++ks)
      asm("" : "+v"(bfrag[t][ks]));

  // ---- stage x (f32, coalesced float4); zero ha ----
  {
    const float4* src0 = (const float4*)(x + (size_t)(b0+0)*TLEN*IDIM);
    const float4* src1 = (const float4*)(x + (size_t)(b0+1)*TLEN*IDIM);
    ((float4*)xs[0])[tid] = src0[tid];
    ((float4*)xs[1])[tid] = src1[tid];
  }
  {
    int* hz = (int*)ha;
    hz[tid] = 0; hz[tid+512] = 0; hz[tid+1024] = 0; hz[tid+1536] = 0;
  }
  __syncthreads();

  float c0 = 0.f, c1 = 0.f, h0o = 0.f, h1o = 0.f;  // lanes l<16
  int tt = dir ? (TLEN-1) : 0;
  const int dt = dir ? -1 : 1;

  const int kse = w >> 1;                                  // ha write ks
  const int Gw0 = ((2*w + (c16 >> 3)) & 3) * 16;           // chain0 row; chain1 = +1
  const int ew  = c16 & 7;

#define STEP(RB, WB)                                                          \
  {                                                                           \
    f16x8 a0 = *(const f16x8*)&ha[RB][0][l][0];                               \
    f16x8 a1 = *(const f16x8*)&ha[RB][1][l][0];                               \
    f16x8 a2 = *(const f16x8*)&ha[RB][2][l][0];                               \
    f16x8 a3 = *(const f16x8*)&ha[RB][3][l][0];                               \
    const float4 xv0 = *(const float4*)&xs[0][tt][0];                         \
    const float4 xv1 = *(const float4*)&xs[1][tt][0];                         \
    f32x4 acc[4];                                                             \
    _Pragma("unroll")                                                         \
    for (int t = 0; t < 4; ++t){                                              \
      float xw0 = fmaf(wih[t].x, xv0.x, fmaf(wih[t].y, xv0.y,                 \
                  fmaf(wih[t].z, xv0.z, fmaf(wih[t].w, xv0.w, bias[t]))));    \
      float xw1 = fmaf(wih[t].x, xv1.x, fmaf(wih[t].y, xv1.y,                 \
                  fmaf(wih[t].z, xv1.z, fmaf(wih[t].w, xv1.w, bias[t]))));    \
      f32x4 ci = { xw0, xw1, 0.f, 0.f };                                      \
      acc[t] = ci;                                                            \
    }                                                                         \
    __builtin_amdgcn_s_setprio(1);                                            \
    _Pragma("unroll")                                                         \
    for (int t = 0; t < 4; ++t){                                              \
      acc[t] = __builtin_amdgcn_mfma_f32_16x16x32_f16(a0, bfrag[t][0], acc[t], 0,0,0); \
      acc[t] = __builtin_amdgcn_mfma_f32_16x16x32_f16(a1, bfrag[t][1], acc[t], 0,0,0); \
      acc[t] = __builtin_amdgcn_mfma_f32_16x16x32_f16(a2, bfrag[t][2], acc[t], 0,0,0); \
      acc[t] = __builtin_amdgcn_mfma_f32_16x16x32_f16(a3, bfrag[t][3], acc[t], 0,0,0); \
    }                                                                         \
    __builtin_amdgcn_s_setprio(0);                                            \
    if (l < 16){                                                              \
      float i0 = sigm(acc[0].x), i1 = sigm(acc[0].y);                         \
      float f0 = sigm(acc[1].x), f1 = sigm(acc[1].y);                         \
      float g0 = tanh_fast(acc[2].x), g1 = tanh_fast(acc[2].y);               \
      float o0 = sigm(acc[3].x), o1 = sigm(acc[3].y);                         \
      c0 = f0*c0 + i0*g0;                                                     \
      c1 = f1*c1 + i1*g1;                                                     \
      h0o = o0 * tanh_fast(c0);                                               \
      h1o = o1 * tanh_fast(c1);                                               \
      ha[WB][kse][Gw0][ew]   = (f16)h0o;                                      \
      ha[WB][kse][Gw0+1][ew] = (f16)h1o;                                      \
    }                                                                         \
    tt += dt;                                                                 \
    __syncthreads();                                                          \
  }

  for (int s = 0; s < TLEN; s += 2){
    STEP(0, 1)
    STEP(1, 0)
  }
#undef STEP

  // final h_T -> out[b, dir*128 + j]
  if (l < 16){
    const int j = w*16 + c16;
    out[(size_t)(b0+0)*(2*HDIM) + dir*HDIM + j] = h0o;
    out[(size_t)(b0+1)*(2*HDIM) + dir*HDIM + j] = h1o;
  }
}

extern "C" void kernel_launch(void* const* d_in, const int* in_sizes, int n_in,
                              void* d_out, int out_size, void* d_ws, size_t ws_size,
                              hipStream_t stream)
{
  const float* x     = (const float*)d_in[0];
  const float* Wih_f = (const float*)d_in[1];
  const float* Whh_f = (const float*)d_in[2];
  const float* bih_f = (const float*)d_in[3];
  const float* bhh_f = (const float*)d_in[4];
  const float* Wih_b = (const float*)d_in[5];
  const float* Whh_b = (const float*)d_in[6];
  const float* bih_b = (const float*)d_in[7];
  const float* bhh_b = (const float*)d_in[8];

  bilstm_v7<<<dim3(256), dim3(512), 0, stream>>>(
      x, Wih_f, Whh_f, bih_f, bhh_f, Wih_b, Whh_b, bih_b, bhh_b,
      (float*)d_out);
}